// Round 9
// baseline (253.778 us; speedup 1.0000x reference)
//
#include <hip/hip_runtime.h>
#include <hip/hip_bf16.h>
#include <stdint.h>

#define B_ 16
#define C_ 256
#define O_ 256
#define H_ 64
#define W_ 64
#define HP 66
#define WP 66
#define HIDDEN 65
#define TEMP 34.0f
#define BK 32

typedef __bf16 bf16x8 __attribute__((ext_vector_type(8)));
typedef float floatx16 __attribute__((ext_vector_type(16)));
typedef unsigned int uint;
typedef unsigned short ushort;

__device__ __forceinline__ ushort f2bf(float f) {
    union { float f; uint32_t u; } v; v.f = f;
    uint32_t u = v.u;
    uint32_t r = (u + 0x7FFFu + ((u >> 16) & 1u)) >> 16;
    return (ushort)r;
}

// ---------------------------------------------------------------------------
// Kernel 1: NCHW fp32 -> zero-padded NHWC bf16 transpose, fused pooling.
// (unchanged)
// ---------------------------------------------------------------------------
#define LTR 132
__global__ __launch_bounds__(256) void pad_pool_kernel(
    const float* __restrict__ x, ushort* __restrict__ xp,
    float* __restrict__ pooled)
{
    int b  = blockIdx.x / HP;
    int hp = blockIdx.x % HP;
    ushort* xpb = xp + ((size_t)(b * HP + hp)) * WP * C_;
    int tid = threadIdx.x;

    if (hp == 0 || hp == HP - 1) {
        uint* p = (uint*)xpb;
        for (int i = tid; i < WP * C_ / 2; i += 256) p[i] = 0;
        return;
    }
    int h = hp - 1;

    __shared__ uint  tr[64 * LTR];
    __shared__ float pr[8 * 256];

    int wq = tid & 15;
    int sw = (wq & 3) << 3;
    const float* xb = x + (((size_t)b * C_) * H_ + h) * W_ + wq * 4;
    #pragma unroll
    for (int i = 0; i < 8; i++) {
        int cp = i * 16 + (tid >> 4);
        const float* p0 = xb + (size_t)(2 * cp) * H_ * W_;
        float4 v0 = *(const float4*)p0;
        float4 v1 = *(const float4*)(p0 + H_ * W_);
        uint r0 = (uint)f2bf(v0.x) | ((uint)f2bf(v1.x) << 16);
        uint r1 = (uint)f2bf(v0.y) | ((uint)f2bf(v1.y) << 16);
        uint r2 = (uint)f2bf(v0.z) | ((uint)f2bf(v1.z) << 16);
        uint r3 = (uint)f2bf(v0.w) | ((uint)f2bf(v1.w) << 16);
        int col = cp ^ sw;
        tr[(wq * 4 + 0) * LTR + col] = r0;
        tr[(wq * 4 + 1) * LTR + col] = r1;
        tr[(wq * 4 + 2) * LTR + col] = r2;
        tr[(wq * 4 + 3) * LTR + col] = r3;
    }

    if (tid < 32) {
        *(uint4*)(xpb + tid * 8) = uint4{0, 0, 0, 0};
    } else if (tid < 64) {
        *(uint4*)(xpb + (size_t)65 * C_ + (tid - 32) * 8) = uint4{0, 0, 0, 0};
    }
    __syncthreads();

    int cg = tid & 31;
    int wg = tid >> 5;
    float acc[8] = {0, 0, 0, 0, 0, 0, 0, 0};
    #pragma unroll
    for (int i = 0; i < 8; i++) {
        int w = i * 8 + wg;
        int s = ((w >> 2) & 3) << 3;
        uint4 d = *(const uint4*)(&tr[w * LTR + ((cg * 4) ^ s)]);
        *(uint4*)(xpb + (size_t)(w + 1) * C_ + cg * 8) = d;
        acc[0] += __uint_as_float(d.x << 16);
        acc[1] += __uint_as_float(d.x & 0xffff0000u);
        acc[2] += __uint_as_float(d.y << 16);
        acc[3] += __uint_as_float(d.y & 0xffff0000u);
        acc[4] += __uint_as_float(d.z << 16);
        acc[5] += __uint_as_float(d.z & 0xffff0000u);
        acc[6] += __uint_as_float(d.w << 16);
        acc[7] += __uint_as_float(d.w & 0xffff0000u);
    }
    #pragma unroll
    for (int k = 0; k < 8; k++) pr[wg * 256 + cg * 8 + k] = acc[k];
    __syncthreads();

    float s = 0.f;
    #pragma unroll
    for (int j = 0; j < 8; j++) s += pr[j * 256 + tid];
    atomicAdd(&pooled[b * C_ + tid], s);
}

// ---------------------------------------------------------------------------
// Kernel 2: fused attention-MLP + weight aggregation.
// aggw written in MFMA-fragment layout [b][tap 9][cc 32][o 256][8]
// (cc = channel/8) — this exact layout+consumer pair passed in the R7 run.
// ---------------------------------------------------------------------------
__global__ __launch_bounds__(256) void att_agg_kernel(
    const float* __restrict__ weight, const float* __restrict__ pooled,
    const float* __restrict__ w1, const float* __restrict__ w2,
    const float* __restrict__ b2, ushort* __restrict__ aggw)
{
    int o = blockIdx.x;
    int tid = threadIdx.x;
    __shared__ float psh[B_ * C_];
    __shared__ float hsh[B_ * HIDDEN];
    __shared__ float a_sh[64];

    for (int i = tid; i < B_ * C_; i += 256) psh[i] = pooled[i] * (1.0f / (H_ * W_));
    __syncthreads();
    for (int i = tid; i < B_ * HIDDEN; i += 256) {
        int bb = i / HIDDEN, j = i % HIDDEN;
        float s = 0.f;
        for (int c = 0; c < C_; c++) s += psh[bb * C_ + c] * w1[j * C_ + c];
        hsh[i] = fmaxf(s, 0.f);
    }
    __syncthreads();
    if (tid < B_) {
        float lg[4];
        float mx = -1e30f;
        for (int k = 0; k < 4; k++) {
            float s = b2[k];
            for (int j = 0; j < HIDDEN; j++) s += hsh[tid * HIDDEN + j] * w2[k * HIDDEN + j];
            lg[k] = s / TEMP;
            mx = fmaxf(mx, lg[k]);
        }
        float den = 0.f;
        for (int k = 0; k < 4; k++) { lg[k] = expf(lg[k] - mx); den += lg[k]; }
        for (int k = 0; k < 4; k++) a_sh[tid * 4 + k] = lg[k] / den;
    }
    __syncthreads();

    int cp = tid & 127, bh = tid >> 7;   // cp = channel-pair (channels 2cp,2cp+1)
    float wv[4][18];
    #pragma unroll
    for (int k = 0; k < 4; k++) {
        const float* wp_ = weight + (((size_t)k * O_ + o) * C_ + cp * 2) * 9;
        #pragma unroll
        for (int t = 0; t < 18; t++) wv[k][t] = wp_[t];
    }
    // fragment layout: uint index = (((b*9+t)*32 + cc)*256 + o)*4 + ue
    //   cc = (2cp)/8 = cp>>2,  ue = ((2cp)%8)/2 = cp&3
    uint* dst = (uint*)aggw;
    for (int b = bh * 8; b < bh * 8 + 8; b++) {
        float a0 = a_sh[b * 4 + 0], a1 = a_sh[b * 4 + 1];
        float a2 = a_sh[b * 4 + 2], a3 = a_sh[b * 4 + 3];
        #pragma unroll
        for (int t = 0; t < 9; t++) {
            float s0 = a0 * wv[0][t]     + a1 * wv[1][t]     + a2 * wv[2][t]     + a3 * wv[3][t];
            float s1 = a0 * wv[0][9 + t] + a1 * wv[1][9 + t] + a2 * wv[2][9 + t] + a3 * wv[3][9 + t];
            uint p = (uint)f2bf(s0) | ((uint)f2bf(s1) << 16);
            dst[((((size_t)b * 9 + t) * 32 + (cp >> 2)) * 256 + o) * 4 + (cp & 3)] = p;
        }
    }
}

// ---------------------------------------------------------------------------
// Kernel 3: conv — R5's verified skeleton (512 thr, 8 waves 4x2, wave-tile
// 64x128, free-flow COMPUTE, B dbuf via global_load_lds + counted vmcnt),
// with ONE change: A-operand read DIRECT from global (fragment-layout aggw,
// two 512B coalesced L2 segments per read, prefetched one group ahead).
// R8 post-mortem: LDS is the single shared CU resource (5100 cyc/step) vs
// 4 parallel MFMA pipes (3072 cyc/step/SIMD); R5 = serial sum (82 µs ✓).
// Removing A from LDS cuts reads 288->192 and DMA 66->17 KB per step:
// LDS/step ~3300 cyc -> serial bound 63 µs, overlap should do better.
// Phase barriers (R8) REVERTED — lockstep hurt (93 µs measured).
// ---------------------------------------------------------------------------
__device__ __forceinline__ void gl_lds16(const ushort* g, ushort* l) {
    __builtin_amdgcn_global_load_lds(
        (__attribute__((address_space(1))) void*)(uintptr_t)g,
        (__attribute__((address_space(3))) void*)l,
        16, 0, 0);
}

__global__ __launch_bounds__(512, 2) void conv_kernel(
    const ushort* __restrict__ xp,    // [B][66][66][C] bf16
    const ushort* __restrict__ aggw,  // [B][9][32][256][8] bf16 (fragment order)
    float* __restrict__ out)          // [B][O][4096]  f32
{
    __shared__ ushort Bs[2][272 * 32];       // 2 x 17408 B

    int bid = blockIdx.x;
    int xcd = bid & 7, sl8 = bid >> 3;       // 256 blocks: bid%8 -> XCD
    int b  = xcd * 2 + (sl8 >> 4);           // each XCD: 2 batches x 16 nt
    int nt = sl8 & 15;
    int r0 = nt * 4;

    int tid = threadIdx.x;
    int wave = tid >> 6, lane = tid & 63;
    int wm = wave >> 1, wn = wave & 1;       // 4x2 wave grid
    int n31 = lane & 31, h = lane >> 5;

    const ushort* gA0 = aggw + (size_t)b * 9 * 32 * 2048;   // fragment layout
    const ushort* gB0 = xp + (size_t)b * HP * WP * C_;

    // --- B staging: 1056 chunks = [rw 264][p 4]; physical slot p holds
    // logical slot s = p ^ ((rw>>1)&3)  (inverse swizzle baked into source).
    int gBoff[2], gBoffT;
    #pragma unroll
    for (int j = 0; j < 2; j++) {
        int i = j * 512 + tid;
        int rw = i >> 2, p = i & 3;
        int sw = p ^ ((rw >> 1) & 3);
        int wr_ = rw / 66, wp = rw - wr_ * 66;
        gBoff[j] = ((r0 + wr_) * WP + wp) * C_ + sw * 8;
    }
    {
        int i = 1024 + lane;                 // tail 32 chunks (wave 0, lane<32)
        int rw = i >> 2, p = i & 3;
        int sw = p ^ ((rw >> 1) & 3);
        int wr_ = rw / 66, wp = rw - wr_ * 66;
        gBoffT = ((r0 + wr_) * WP + wp) * C_ + sw * 8;
    }

    // --- B fragment read offsets (ushort units); ks toggles slot via ^16
    int bOff[3][4];
    #pragma unroll
    for (int tx = 0; tx < 3; tx++)
        #pragma unroll
        for (int jn = 0; jn < 4; jn++) {
            int nb = wn * 128 + jn * 32;
            int rw = (nb >> 6) * 66 + (nb & 63) + tx + n31;
            bOff[tx][jn] = rw * 32 + ((h ^ ((rw >> 1) & 3)) << 3);
        }

    // --- A per-lane base inside a (tap, cc-chunk): lane(n31,h) reads
    // chunk +h, row wm*64 + im*32 + n31. chunk stride = 2048 ushorts.
    int aLane = h * 2048 + (wm * 64 + n31) * 8;

    floatx16 acc[2][4] = {};   // 128 accumulator regs

    ushort* B0 = &Bs[0][0]; ushort* B1 = &Bs[1][0];

    auto ISSUE = [&](int t, ushort* Bw) {
        int tyn = t >> 3, cn = (t & 7) * BK;
        const ushort* gB = gB0 + (size_t)tyn * WP * C_ + cn;
        #pragma unroll
        for (int j = 0; j < 2; j++)
            gl_lds16(gB + gBoff[j], Bw + (j * 8 + wave) * 512);
        if (wave == 0 && lane < 32)
            gl_lds16(gB + gBoffT, Bw + 16 * 512);
    };

    // free-flow: per group {2 A global loads (prefetched 1 group ahead),
    // 4 B ds_reads, 8 MFMA}; compiler schedules, 2 waves/SIMD slip.
    auto COMPUTE = [&](int t, const ushort* Bq) {
        int tyn = t >> 3, ccb = (t & 7) * 4;
        const ushort* gA = gA0 + ((size_t)(tyn * 3) * 32 + ccb) * 2048 + aLane;
        // group g: tx=g>>1, ks=g&1; chunk offset = (tx*32 + 2*ks)*2048
        bf16x8 cA0 = *(const bf16x8*)(gA);
        bf16x8 cA1 = *(const bf16x8*)(gA + 256);
        #pragma unroll
        for (int g = 0; g < 6; g++) {
            const int tx = g >> 1, ks = g & 1, kx = ks << 4;
            bf16x8 nA0, nA1;
            if (g < 5) {
                const int gn = g + 1;
                const size_t offn = (size_t)((gn >> 1) * 32 + (gn & 1) * 2) * 2048;
                nA0 = *(const bf16x8*)(gA + offn);
                nA1 = *(const bf16x8*)(gA + offn + 256);
            }
            bf16x8 bv[4];
            #pragma unroll
            for (int jn = 0; jn < 4; jn++)
                bv[jn] = *(const bf16x8*)(Bq + (bOff[tx][jn] ^ kx));
            #pragma unroll
            for (int jn = 0; jn < 4; jn++)
                acc[0][jn] = __builtin_amdgcn_mfma_f32_32x32x16_bf16(cA0, bv[jn], acc[0][jn], 0, 0, 0);
            #pragma unroll
            for (int jn = 0; jn < 4; jn++)
                acc[1][jn] = __builtin_amdgcn_mfma_f32_32x32x16_bf16(cA1, bv[jn], acc[1][jn], 0, 0, 0);
            if (g < 5) { cA0 = nA0; cA1 = nA1; }
        }
    };

    // prologue: two B batches in flight
    ISSUE(0, B0);
    ISSUE(1, B1);

    // main loop, 24 steps, last pair peeled. vmcnt(2) = drain the oldest
    // B batch only (keep next batch flying); A loads are compiler-managed.
    for (int s = 0; s < 22; s += 2) {
        asm volatile("s_waitcnt vmcnt(2)" ::: "memory");
        __builtin_amdgcn_s_barrier();
        COMPUTE(s, B0);
        __builtin_amdgcn_s_barrier();
        ISSUE(s + 2, B0);

        asm volatile("s_waitcnt vmcnt(2)" ::: "memory");
        __builtin_amdgcn_s_barrier();
        COMPUTE(s + 1, B1);
        __builtin_amdgcn_s_barrier();
        ISSUE(s + 3, B1);
    }
    asm volatile("s_waitcnt vmcnt(2)" ::: "memory");
    __builtin_amdgcn_s_barrier();
    COMPUTE(22, B0);
    asm volatile("s_waitcnt vmcnt(0)" ::: "memory");
    __builtin_amdgcn_s_barrier();
    COMPUTE(23, B1);

    // --- epilogue: C/D col=lane&31, row=(reg&3)+8*(reg>>2)+4*h (verified)
    float* outb = out + (size_t)b * O_ * (H_ * W_) + (size_t)nt * 256;
    #pragma unroll
    for (int im = 0; im < 2; im++) {
        int obase = wm * 64 + im * 32 + 4 * h;
        #pragma unroll
        for (int jn = 0; jn < 4; jn++) {
            int pcol = wn * 128 + jn * 32 + n31;
            #pragma unroll
            for (int g = 0; g < 4; g++)
                #pragma unroll
                for (int r4 = 0; r4 < 4; r4++)
                    outb[(size_t)(obase + r4 + 8 * g) * (H_ * W_) + pcol] = acc[im][jn][g * 4 + r4];
        }
    }
}

// ---------------------------------------------------------------------------
extern "C" void kernel_launch(void* const* d_in, const int* in_sizes, int n_in,
                              void* d_out, int out_size, void* d_ws, size_t ws_size,
                              hipStream_t stream) {
    const float* x      = (const float*)d_in[0];
    const float* weight = (const float*)d_in[1];
    const float* att_w1 = (const float*)d_in[2];
    const float* att_w2 = (const float*)d_in[3];
    const float* att_b2 = (const float*)d_in[4];
    float* out = (float*)d_out;

    char* ws = (char*)d_ws;
    float* pooled  = (float*)ws;                                  // 16 KiB
    ushort* aggw   = (ushort*)(ws + 32768);                       // 18,874,368 B
    ushort* xp     = (ushort*)(ws + 32768 + 18874368);            // 35,684,352 B

    hipMemsetAsync(pooled, 0, B_ * C_ * sizeof(float), stream);
    pad_pool_kernel<<<B_ * HP, 256, 0, stream>>>(x, xp, pooled);
    att_agg_kernel<<<O_, 256, 0, stream>>>(weight, pooled, att_w1, att_w2, att_b2, aggw);
    conv_kernel<<<256, 512, 0, stream>>>(xp, aggw, out);
}

// Round 10
// 207.041 us; speedup vs baseline: 1.2257x; 1.2257x over previous
//
#include <hip/hip_runtime.h>
#include <hip/hip_bf16.h>
#include <stdint.h>

#define B_ 16
#define C_ 256
#define O_ 256
#define H_ 64
#define W_ 64
#define HP 66
#define WP 66
#define HIDDEN 65
#define TEMP 34.0f
#define BK 32

typedef __bf16 bf16x8 __attribute__((ext_vector_type(8)));
typedef float floatx16 __attribute__((ext_vector_type(16)));
typedef unsigned int uint;
typedef unsigned short ushort;

__device__ __forceinline__ ushort f2bf(float f) {
    union { float f; uint32_t u; } v; v.f = f;
    uint32_t u = v.u;
    uint32_t r = (u + 0x7FFFu + ((u >> 16) & 1u)) >> 16;
    return (ushort)r;
}

// ---------------------------------------------------------------------------
// Kernel 1: NCHW fp32 -> zero-padded NHWC bf16 transpose, fused pooling.
// (unchanged, verified)
// ---------------------------------------------------------------------------
#define LTR 132
__global__ __launch_bounds__(256) void pad_pool_kernel(
    const float* __restrict__ x, ushort* __restrict__ xp,
    float* __restrict__ pooled)
{
    int b  = blockIdx.x / HP;
    int hp = blockIdx.x % HP;
    ushort* xpb = xp + ((size_t)(b * HP + hp)) * WP * C_;
    int tid = threadIdx.x;

    if (hp == 0 || hp == HP - 1) {
        uint* p = (uint*)xpb;
        for (int i = tid; i < WP * C_ / 2; i += 256) p[i] = 0;
        return;
    }
    int h = hp - 1;

    __shared__ uint  tr[64 * LTR];
    __shared__ float pr[8 * 256];

    int wq = tid & 15;
    int sw = (wq & 3) << 3;
    const float* xb = x + (((size_t)b * C_) * H_ + h) * W_ + wq * 4;
    #pragma unroll
    for (int i = 0; i < 8; i++) {
        int cp = i * 16 + (tid >> 4);
        const float* p0 = xb + (size_t)(2 * cp) * H_ * W_;
        float4 v0 = *(const float4*)p0;
        float4 v1 = *(const float4*)(p0 + H_ * W_);
        uint r0 = (uint)f2bf(v0.x) | ((uint)f2bf(v1.x) << 16);
        uint r1 = (uint)f2bf(v0.y) | ((uint)f2bf(v1.y) << 16);
        uint r2 = (uint)f2bf(v0.z) | ((uint)f2bf(v1.z) << 16);
        uint r3 = (uint)f2bf(v0.w) | ((uint)f2bf(v1.w) << 16);
        int col = cp ^ sw;
        tr[(wq * 4 + 0) * LTR + col] = r0;
        tr[(wq * 4 + 1) * LTR + col] = r1;
        tr[(wq * 4 + 2) * LTR + col] = r2;
        tr[(wq * 4 + 3) * LTR + col] = r3;
    }

    if (tid < 32) {
        *(uint4*)(xpb + tid * 8) = uint4{0, 0, 0, 0};
    } else if (tid < 64) {
        *(uint4*)(xpb + (size_t)65 * C_ + (tid - 32) * 8) = uint4{0, 0, 0, 0};
    }
    __syncthreads();

    int cg = tid & 31;
    int wg = tid >> 5;
    float acc[8] = {0, 0, 0, 0, 0, 0, 0, 0};
    #pragma unroll
    for (int i = 0; i < 8; i++) {
        int w = i * 8 + wg;
        int s = ((w >> 2) & 3) << 3;
        uint4 d = *(const uint4*)(&tr[w * LTR + ((cg * 4) ^ s)]);
        *(uint4*)(xpb + (size_t)(w + 1) * C_ + cg * 8) = d;
        acc[0] += __uint_as_float(d.x << 16);
        acc[1] += __uint_as_float(d.x & 0xffff0000u);
        acc[2] += __uint_as_float(d.y << 16);
        acc[3] += __uint_as_float(d.y & 0xffff0000u);
        acc[4] += __uint_as_float(d.z << 16);
        acc[5] += __uint_as_float(d.z & 0xffff0000u);
        acc[6] += __uint_as_float(d.w << 16);
        acc[7] += __uint_as_float(d.w & 0xffff0000u);
    }
    #pragma unroll
    for (int k = 0; k < 8; k++) pr[wg * 256 + cg * 8 + k] = acc[k];
    __syncthreads();

    float s = 0.f;
    #pragma unroll
    for (int j = 0; j < 8; j++) s += pr[j * 256 + tid];
    atomicAdd(&pooled[b * C_ + tid], s);
}

// ---------------------------------------------------------------------------
// Kernel 2a (NEW): attention MLP + softmax, computed ONCE (16 blocks, one
// per batch). Previously every agg block (256) redundantly recomputed this
// with per-scalar uncoalesced w1 reads — the prime k2 latency suspect.
// w1 staged coalesced into LDS with +1 padding (row stride 257 -> the
// 65-lane dot loop is bank-conflict-free). FP accumulation order identical
// to the old kernel (c ascending, j ascending).
// ---------------------------------------------------------------------------
__global__ __launch_bounds__(256) void att_kernel(
    const float* __restrict__ pooled, const float* __restrict__ w1,
    const float* __restrict__ w2, const float* __restrict__ b2,
    float* __restrict__ att)
{
    int b = blockIdx.x;
    int tid = threadIdx.x;
    __shared__ float w1s[HIDDEN * 257];   // 66.8 KB, padded rows
    __shared__ float psh[C_];
    __shared__ float hsh[HIDDEN];
    __shared__ float lgs[4];

    psh[tid] = pooled[b * C_ + tid] * (1.0f / (H_ * W_));
    for (int i = tid; i < HIDDEN * C_; i += 256) {
        int j = i >> 8, c = i & 255;
        w1s[j * 257 + c] = w1[i];        // coalesced global read
    }
    __syncthreads();
    if (tid < HIDDEN) {
        float s = 0.f;
        for (int c = 0; c < C_; c++) s += psh[c] * w1s[tid * 257 + c];
        hsh[tid] = fmaxf(s, 0.f);
    }
    __syncthreads();
    if (tid < 4) {
        float s = b2[tid];
        for (int j = 0; j < HIDDEN; j++) s += hsh[j] * w2[tid * HIDDEN + j];
        lgs[tid] = s / TEMP;
    }
    __syncthreads();
    if (tid == 0) {
        float mx = fmaxf(fmaxf(lgs[0], lgs[1]), fmaxf(lgs[2], lgs[3]));
        float e[4]; float den = 0.f;
        #pragma unroll
        for (int k = 0; k < 4; k++) { e[k] = expf(lgs[k] - mx); den += e[k]; }
        #pragma unroll
        for (int k = 0; k < 4; k++) att[b * 4 + k] = e[k] / den;
    }
}

// ---------------------------------------------------------------------------
// Kernel 2b: weight aggregation — R5's verified tail verbatim, MLP replaced
// by a 64-float att read. aggw layout [b][9][O][C] (R5 conv-compatible).
// ---------------------------------------------------------------------------
__global__ __launch_bounds__(256) void agg_kernel(
    const float* __restrict__ weight, const float* __restrict__ att,
    ushort* __restrict__ aggw)
{
    int o = blockIdx.x;
    int tid = threadIdx.x;
    __shared__ float a_sh[64];
    if (tid < 64) a_sh[tid] = att[tid];
    __syncthreads();

    int cp = tid & 127, bh = tid >> 7;
    float wv[4][18];
    #pragma unroll
    for (int k = 0; k < 4; k++) {
        const float* wp_ = weight + (((size_t)k * O_ + o) * C_ + cp * 2) * 9;
        #pragma unroll
        for (int t = 0; t < 18; t++) wv[k][t] = wp_[t];
    }
    uint* dst = (uint*)aggw;
    for (int b = bh * 8; b < bh * 8 + 8; b++) {
        float a0 = a_sh[b * 4 + 0], a1 = a_sh[b * 4 + 1];
        float a2 = a_sh[b * 4 + 2], a3 = a_sh[b * 4 + 3];
        #pragma unroll
        for (int t = 0; t < 9; t++) {
            float s0 = a0 * wv[0][t]     + a1 * wv[1][t]     + a2 * wv[2][t]     + a3 * wv[3][t];
            float s1 = a0 * wv[0][9 + t] + a1 * wv[1][9 + t] + a2 * wv[2][9 + t] + a3 * wv[3][9 + t];
            uint p = (uint)f2bf(s0) | ((uint)f2bf(s1) << 16);
            dst[(((size_t)b * 9 + t) * O_ + o) * (C_ / 2) + cp] = p;
        }
    }
}

// ---------------------------------------------------------------------------
// Kernel 3: conv — VERIFIED R5 version restored verbatim (80.6 µs, MfmaUtil
// 41%). R6 (1 wave/SIMD), R8 (phase barriers), R9 (A-from-global) all
// regressed; the 2-wave/SIMD free-flow loop with counted vmcnt(8) is the
// best measured structure for this kernel. Conv optimization is parked
// until the (larger) preprocessing cost is fixed.
// ---------------------------------------------------------------------------
__device__ __forceinline__ void gl_lds16(const ushort* g, ushort* l) {
    __builtin_amdgcn_global_load_lds(
        (__attribute__((address_space(1))) void*)(uintptr_t)g,
        (__attribute__((address_space(3))) void*)l,
        16, 0, 0);
}

__global__ __launch_bounds__(512, 2) void conv_kernel(
    const ushort* __restrict__ xp,    // [B][66][66][C] bf16
    const ushort* __restrict__ aggw,  // [B][9][O][C]  bf16
    float* __restrict__ out)          // [B][O][4096]  f32
{
    __shared__ ushort As[2][3 * 256 * 32];   // 2 x 49152 B, linear [tt][row][4 slots]
    __shared__ ushort Bs[2][272 * 32];       // 2 x 17408 B (264 used rows + pad)

    int bid = blockIdx.x;
    int xcd = bid & 7, sl8 = bid >> 3;       // 256 blocks: bid%8 -> XCD
    int b  = xcd * 2 + (sl8 >> 4);           // each XCD: 2 batches x 16 nt
    int nt = sl8 & 15;
    int r0 = nt * 4;

    int tid = threadIdx.x;
    int wave = tid >> 6, lane = tid & 63;
    int wm = wave >> 1, wn = wave & 1;       // 4x2 wave grid
    int n31 = lane & 31, h = lane >> 5;

    const ushort* gA0 = aggw + (size_t)b * 9 * O_ * C_;
    const ushort* gB0 = xp + (size_t)b * HP * WP * C_;

    // --- staging: per-lane global offsets with INVERSE swizzle baked in.
    int gAoff[6];
    #pragma unroll
    for (int j = 0; j < 6; j++) {
        int i = j * 512 + tid;               // 3072 chunks = [tt 3][row 256][p 4]
        int tt = i >> 10, rem = i & 1023;
        int row = rem >> 2, p = rem & 3;
        int sw = p ^ ((row >> 1) & 3);
        gAoff[j] = (tt * O_ + row) * C_ + sw * 8;
    }
    int gBoff[2], gBoffT;
    #pragma unroll
    for (int j = 0; j < 2; j++) {
        int i = j * 512 + tid;               // 1056 chunks = [rw 264][p 4]
        int rw = i >> 2, p = i & 3;
        int sw = p ^ ((rw >> 1) & 3);
        int wr_ = rw / 66, wp = rw - wr_ * 66;
        gBoff[j] = ((r0 + wr_) * WP + wp) * C_ + sw * 8;
    }
    {
        int i = 1024 + lane;                 // tail 32 chunks (wave 0, lane<32)
        int rw = i >> 2, p = i & 3;
        int sw = p ^ ((rw >> 1) & 3);
        int wr_ = rw / 66, wp = rw - wr_ * 66;
        gBoffT = ((r0 + wr_) * WP + wp) * C_ + sw * 8;
    }

    // --- fragment read offsets (ushort units), ks=0; ks=1 is offset ^ 16
    int aOff[2];
    #pragma unroll
    for (int im = 0; im < 2; im++) {
        int row = wm * 64 + im * 32 + n31;
        aOff[im] = row * 32 + ((h ^ ((row >> 1) & 3)) << 3);
    }
    int bOff[3][4];
    #pragma unroll
    for (int tx = 0; tx < 3; tx++)
        #pragma unroll
        for (int jn = 0; jn < 4; jn++) {
            int nb = wn * 128 + jn * 32;
            int rw = (nb >> 6) * 66 + (nb & 63) + tx + n31;
            bOff[tx][jn] = rw * 32 + ((h ^ ((rw >> 1) & 3)) << 3);
        }

    floatx16 acc[2][4] = {};   // 128 accumulator regs

    ushort* A0 = &As[0][0]; ushort* A1 = &As[1][0];
    ushort* B0 = &Bs[0][0]; ushort* B1 = &Bs[1][0];

    auto ISSUE = [&](int t, ushort* Aw, ushort* Bw) {
        int tyn = t >> 3, cn = (t & 7) * BK;
        const ushort* gA = gA0 + (size_t)(tyn * 3) * O_ * C_ + cn;
        const ushort* gB = gB0 + (size_t)tyn * WP * C_ + cn;
        #pragma unroll
        for (int j = 0; j < 6; j++)
            gl_lds16(gA + gAoff[j], Aw + (j * 8 + wave) * 512);
        #pragma unroll
        for (int j = 0; j < 2; j++)
            gl_lds16(gB + gBoff[j], Bw + (j * 8 + wave) * 512);
        if (wave == 0 && lane < 32)
            gl_lds16(gB + gBoffT, Bw + 16 * 512);
    };

    auto COMPUTE = [&](const ushort* Aq, const ushort* Bq) {
        __builtin_amdgcn_s_setprio(1);
        #pragma unroll
        for (int tx = 0; tx < 3; tx++) {
            #pragma unroll
            for (int ks = 0; ks < 2; ks++) {
                const int kx = ks << 4;      // slot(ks=1) = slot(ks=0) ^ 2
                bf16x8 af0 = *(const bf16x8*)(Aq + tx * 8192 + (aOff[0] ^ kx));
                bf16x8 af1 = *(const bf16x8*)(Aq + tx * 8192 + (aOff[1] ^ kx));
                bf16x8 bv[4];
                #pragma unroll
                for (int jn = 0; jn < 4; jn++)
                    bv[jn] = *(const bf16x8*)(Bq + (bOff[tx][jn] ^ kx));
                #pragma unroll
                for (int jn = 0; jn < 4; jn++)
                    acc[0][jn] = __builtin_amdgcn_mfma_f32_32x32x16_bf16(af0, bv[jn], acc[0][jn], 0, 0, 0);
                #pragma unroll
                for (int jn = 0; jn < 4; jn++)
                    acc[1][jn] = __builtin_amdgcn_mfma_f32_32x32x16_bf16(af1, bv[jn], acc[1][jn], 0, 0, 0);
            }
        }
        __builtin_amdgcn_s_setprio(0);
    };

    // prologue: two batches in flight
    ISSUE(0, A0, B0);
    ISSUE(1, A1, B1);

    // main loop, 24 steps, last pair peeled. vmcnt(8) = drain oldest batch
    // only (current buffer's loads), keep next batch flying across barriers.
    for (int s = 0; s < 22; s += 2) {
        asm volatile("s_waitcnt vmcnt(8)" ::: "memory");
        __builtin_amdgcn_s_barrier();
        COMPUTE(A0, B0);
        __builtin_amdgcn_s_barrier();
        ISSUE(s + 2, A0, B0);

        asm volatile("s_waitcnt vmcnt(8)" ::: "memory");
        __builtin_amdgcn_s_barrier();
        COMPUTE(A1, B1);
        __builtin_amdgcn_s_barrier();
        ISSUE(s + 3, A1, B1);
    }
    asm volatile("s_waitcnt vmcnt(8)" ::: "memory");
    __builtin_amdgcn_s_barrier();
    COMPUTE(A0, B0);                          // step 22
    asm volatile("s_waitcnt vmcnt(0)" ::: "memory");
    __builtin_amdgcn_s_barrier();
    COMPUTE(A1, B1);                          // step 23

    // --- epilogue: C/D col=lane&31, row=(reg&3)+8*(reg>>2)+4*h (verified)
    float* outb = out + (size_t)b * O_ * (H_ * W_) + (size_t)nt * 256;
    #pragma unroll
    for (int im = 0; im < 2; im++) {
        int obase = wm * 64 + im * 32 + 4 * h;
        #pragma unroll
        for (int jn = 0; jn < 4; jn++) {
            int pcol = wn * 128 + jn * 32 + n31;
            #pragma unroll
            for (int g = 0; g < 4; g++)
                #pragma unroll
                for (int r4 = 0; r4 < 4; r4++)
                    outb[(size_t)(obase + r4 + 8 * g) * (H_ * W_) + pcol] = acc[im][jn][g * 4 + r4];
        }
    }
}

// ---------------------------------------------------------------------------
extern "C" void kernel_launch(void* const* d_in, const int* in_sizes, int n_in,
                              void* d_out, int out_size, void* d_ws, size_t ws_size,
                              hipStream_t stream) {
    const float* x      = (const float*)d_in[0];
    const float* weight = (const float*)d_in[1];
    const float* att_w1 = (const float*)d_in[2];
    const float* att_w2 = (const float*)d_in[3];
    const float* att_b2 = (const float*)d_in[4];
    float* out = (float*)d_out;

    char* ws = (char*)d_ws;
    float* pooled  = (float*)ws;                                  // 16 KiB
    float* att     = (float*)(ws + 16384);                        // 256 B
    ushort* aggw   = (ushort*)(ws + 32768);                       // 18,874,368 B
    ushort* xp     = (ushort*)(ws + 32768 + 18874368);            // 35,684,352 B

    hipMemsetAsync(pooled, 0, B_ * C_ * sizeof(float), stream);
    pad_pool_kernel<<<B_ * HP, 256, 0, stream>>>(x, xp, pooled);
    att_kernel<<<B_, 256, 0, stream>>>(pooled, att_w1, att_w2, att_b2, att);
    agg_kernel<<<O_, 256, 0, stream>>>(weight, att, aggw);
    conv_kernel<<<256, 512, 0, stream>>>(xp, aggw, out);
}